// Round 3
// baseline (900.730 us; speedup 1.0000x reference)
//
#include <hip/hip_runtime.h>
#include <hip/hip_bf16.h>

#define N_NODES 100000
#define N_HEDGES 100000
#define N_INC 1600000
#define D 128

#define B_KEYS 512            // keys per bucket
#define NBUCK 196             // ceil(100000/512)
#define CAP 10240             // bucket capacity (mean 8192, sigma ~90)
#define CHUNK 4096            // 16 items per thread, register-resident
#define NBLKA ((N_INC + CHUNK - 1) / CHUNK)   // 391

#define LDA 136               // padded bf16 row stride for GEMM LDS tiles

// ---- feature-sliced planar layout: 8 planes of 16 features (32 B) ----
// plane s is a contiguous 3.2 MB region -> L2-resident on the XCD that owns
// slice s (blockIdx & 7 ~ XCD round-robin). Round-1/2 proof: FETCH_SIZE
// dropped 181 MB -> 43 MB (= index stream only), planes L2-resident.
#define NSLICE 8
#define PLANE_SHORTS ((size_t)N_NODES * 16)
#define PLANE_BYTES  ((size_t)N_NODES * 32)
#define GBLK 782              // ceil(100000 / 128) segments-per-block groups

typedef __attribute__((ext_vector_type(8))) short bf16x8;
typedef __attribute__((ext_vector_type(4))) float f32x4;

__device__ __forceinline__ short f2bf(float v) {
    __hip_bfloat16 b = __float2bfloat16(v);
    return *(short*)&b;
}
__device__ __forceinline__ unsigned packbf2(float x, float y) {
    __hip_bfloat162 p = __float22bfloat162_rn(make_float2(x, y));
    return *(unsigned*)&p;
}

// ---------------- W transpose + bf16 convert (once per call) ----------------
__global__ void wt_kernel(const float* __restrict__ W1, const float* __restrict__ W2,
                          short* __restrict__ WT1, short* __restrict__ WT2,
                          int* __restrict__ gcnt) {
    if (blockIdx.x == 0) {
        for (int i = threadIdx.x; i < 2 * NBUCK; i += 256) gcnt[i] = 0;
    }
    int idx = blockIdx.x * 256 + threadIdx.x;     // 0..32767
    int sel = idx >> 14;
    int li = idx & 16383;
    int n = li >> 7, k = li & 127;
    const float* src = sel ? W2 : W1;
    short* dst = sel ? WT2 : WT1;
    dst[li] = f2bf(src[k * 128 + n]);
}

// ---------------- Phase A: bucket partition, register-resident chunk ----------------
__launch_bounds__(256)
__global__ void binA_kernel(const int* __restrict__ nidx, const int* __restrict__ hidx,
                            int* __restrict__ gcnt_e, int* __restrict__ gcnt_n,
                            unsigned* __restrict__ bin_e, unsigned* __restrict__ bin_n) {
    __shared__ int hist_e[NBUCK], hist_n[NBUCK], base_e[NBUCK], base_n[NBUCK];
    int t = threadIdx.x;
    int items_h[16], items_n[16];
    int start = blockIdx.x * CHUNK;
#pragma unroll
    for (int k = 0; k < 16; ++k) {
        int i = start + t + k * 256;
        bool ok = i < N_INC;
        items_h[k] = ok ? hidx[i] : -1;
        items_n[k] = ok ? nidx[i] : -1;
    }
    for (int b = t; b < NBUCK; b += 256) { hist_e[b] = 0; hist_n[b] = 0; }
    __syncthreads();
#pragma unroll
    for (int k = 0; k < 16; ++k) {
        if (items_h[k] >= 0) {
            atomicAdd(&hist_e[items_h[k] >> 9], 1);
            atomicAdd(&hist_n[items_n[k] >> 9], 1);
        }
    }
    __syncthreads();
    for (int b = t; b < NBUCK; b += 256) {
        base_e[b] = atomicAdd(&gcnt_e[b], hist_e[b]);
        base_n[b] = atomicAdd(&gcnt_n[b], hist_n[b]);
        hist_e[b] = 0; hist_n[b] = 0;
    }
    __syncthreads();
#pragma unroll
    for (int k = 0; k < 16; ++k) {
        if (items_h[k] >= 0) {
            int h = items_h[k], n = items_n[k];
            int be = h >> 9, bn = n >> 9;
            int oe = base_e[be] + atomicAdd(&hist_e[be], 1);
            if (oe >= 0 && oe < CAP) bin_e[(size_t)be * CAP + oe] = ((unsigned)(h & 511) << 17) | (unsigned)n;
            int on = base_n[bn] + atomicAdd(&hist_n[bn], 1);
            if (on >= 0 && on < CAP) bin_n[(size_t)bn * CAP + on] = ((unsigned)(n & 511) << 17) | (unsigned)h;
        }
    }
}

// ---------------- Phase B: per-bucket counting sort, wave-shuffle scan ----------
__launch_bounds__(512)
__global__ void binB2_kernel(const int* __restrict__ gcnt_e, const unsigned* __restrict__ bin_e,
                             int* __restrict__ csr_e, int2* __restrict__ meta_e,
                             const int* __restrict__ gcnt_n, const unsigned* __restrict__ bin_n,
                             int* __restrict__ csr_n, int2* __restrict__ meta_n) {
    __shared__ int kc[B_KEYS];
    __shared__ int wsum[8];
    int b = blockIdx.x;
    const int* gcnt;  const unsigned* bin;  int* csr;  int2* meta;
    if (b < NBUCK) { gcnt = gcnt_e; bin = bin_e; csr = csr_e; meta = meta_e; }
    else { b -= NBUCK; gcnt = gcnt_n; bin = bin_n; csr = csr_n; meta = meta_n; }
    int t = threadIdx.x;
    int lane = t & 63, wv = t >> 6;
    int cnt = gcnt[b];
    if (cnt > CAP) cnt = CAP;
    kc[t] = 0;
    __syncthreads();
    const unsigned* items = bin + (size_t)b * CAP;
    for (int i = t; i < cnt; i += 512) atomicAdd(&kc[items[i] >> 17], 1);
    __syncthreads();
    int mycnt = kc[t];
    int v = mycnt;
#pragma unroll
    for (int off = 1; off < 64; off <<= 1) {
        int u = __shfl_up(v, off);
        if (lane >= off) v += u;
    }
    if (lane == 63) wsum[wv] = v;
    __syncthreads();
    int addp = 0;
#pragma unroll
    for (int w = 0; w < 7; ++w) addp += (w < wv) ? wsum[w] : 0;
    int incl = v + addp;
    int sstart = b * CAP + (incl - mycnt);   // exclusive start
    meta[b * B_KEYS + t] = make_int2(sstart, mycnt);
    kc[t] = sstart;
    __syncthreads();
    for (int i = t; i < cnt; i += 512) {
        unsigned it = items[i];
        int pos = atomicAdd(&kc[it >> 17], 1);
        csr[pos] = (int)(it & 0x1FFFFu);
    }
}

// ---------------- MFMA bf16 GEMM: planar output [8][N][16 feats] ----------------
template <bool PLANAR>
__launch_bounds__(256)
__global__ void gemm_mfma_kernel(const void* __restrict__ Xv, const short* __restrict__ WT,
                                 char* __restrict__ Y, int nrows) {
    __shared__ short lds_w[128 * LDA];   // W^T [n][k]; later reused for C staging
    int tid = threadIdx.x;
    int row0 = blockIdx.x * 64;

    {
        const uint4* w4 = (const uint4*)WT;
#pragma unroll
        for (int i = 0; i < 8; ++i) {
            int idx = tid + i * 256;          // 0..2047 = 128 rows x 16 uint4
            int n = idx >> 4, g = idx & 15;
            *(uint4*)(lds_w + n * LDA + g * 8) = w4[idx];
        }
    }

    int wv = tid >> 6, lane = tid & 63;
    int m = lane & 15, quad = lane >> 4;
    int row = row0 + wv * 16 + m;
    bool rowok = row < nrows;

    bf16x8 af[4];
    if constexpr (!PLANAR) {
        const float* xr = (const float*)Xv + (size_t)row * 128 + quad * 8;
#pragma unroll
        for (int k0 = 0; k0 < 4; ++k0) {
            float4 a0 = make_float4(0.f, 0.f, 0.f, 0.f), a1 = a0;
            if (rowok) {
                a0 = *(const float4*)(xr + k0 * 32);
                a1 = *(const float4*)(xr + k0 * 32 + 4);
            }
            bf16x8 f;
            f[0] = f2bf(a0.x); f[1] = f2bf(a0.y); f[2] = f2bf(a0.z); f[3] = f2bf(a0.w);
            f[4] = f2bf(a1.x); f[5] = f2bf(a1.y); f[6] = f2bf(a1.z); f[7] = f2bf(a1.w);
            af[k0] = f;
        }
    } else {
        const short* X = (const short*)Xv;
#pragma unroll
        for (int k0 = 0; k0 < 4; ++k0) {
            int p = k0 * 2 + (quad >> 1);
            bf16x8 f = {0, 0, 0, 0, 0, 0, 0, 0};
            if (rowok) f = *(const bf16x8*)(X + (size_t)p * PLANE_SHORTS + (size_t)row * 16 + (quad & 1) * 8);
            af[k0] = f;
        }
    }
    __syncthreads();   // W staged

    f32x4 zero = {0.f, 0.f, 0.f, 0.f};
    f32x4 acc[8];
#pragma unroll
    for (int t8 = 0; t8 < 8; ++t8) acc[t8] = zero;

#pragma unroll
    for (int t8 = 0; t8 < 8; ++t8) {
        const short* brow = lds_w + (t8 * 16 + m) * LDA + quad * 8;
#pragma unroll
        for (int k0 = 0; k0 < 4; ++k0) {
            bf16x8 bf = *(const bf16x8*)(brow + k0 * 32);
            acc[t8] = __builtin_amdgcn_mfma_f32_16x16x32_bf16(af[k0], bf, acc[t8], 0, 0, 0);
        }
    }

    __syncthreads();   // all W ds_reads done; reuse lds_w for C staging
    // C/D layout: col = lane&15, row = quad*4 + reg
#pragma unroll
    for (int t8 = 0; t8 < 8; ++t8) {
#pragma unroll
        for (int r = 0; r < 4; ++r) {
            int crow = wv * 16 + quad * 4 + r;
            int col = t8 * 16 + m;
            lds_w[crow * LDA + col] = f2bf(acc[t8][r]);
        }
    }
    __syncthreads();
    // planar store: per wave one plane, 64 rows x 2 halves = 1 KB contiguous
#pragma unroll
    for (int i = 0; i < 4; ++i) {
        int idx = tid + i * 256;              // 0..1023
        int slice = idx >> 7, j = idx & 127;  // j = row*2 + half
        int r = j >> 1, h = j & 1;
        if (row0 + r < nrows) {
            uint4 u = *(const uint4*)(lds_w + r * LDA + slice * 16 + h * 8);
            *(uint4*)(Y + (size_t)slice * PLANE_BYTES + (size_t)(row0 + r) * 32 + h * 16) = u;
        }
    }
}

// ---------------- lane-owns-segment sliced gather-sum ----------------
__device__ __forceinline__ void acc8_fma(float* a, uint4 u, float msk) {
    a[0] = fmaf(msk, __uint_as_float(u.x << 16), a[0]);
    a[1] = fmaf(msk, __uint_as_float(u.x & 0xFFFF0000u), a[1]);
    a[2] = fmaf(msk, __uint_as_float(u.y << 16), a[2]);
    a[3] = fmaf(msk, __uint_as_float(u.y & 0xFFFF0000u), a[3]);
    a[4] = fmaf(msk, __uint_as_float(u.z << 16), a[4]);
    a[5] = fmaf(msk, __uint_as_float(u.z & 0xFFFF0000u), a[5]);
    a[6] = fmaf(msk, __uint_as_float(u.w << 16), a[6]);
    a[7] = fmaf(msk, __uint_as_float(u.w & 0xFFFF0000u), a[7]);
}

// MODE 0: edge agg (scale only, planar bf16 out)
// MODE 1: node agg + bias + relu (planar bf16 out)
// MODE 2: node agg + bias + relu -> per-block 16-col partials (dst = float*)
//
// Round-3 structure: 2 lanes per segment (one 16 B half each), 32 segs/wave,
// 128 segs/block, one-shot grid. Lane-local accumulation: no shuffle reduce,
// no tail path (mask folded into fma), coalesced stores. 64+ independent
// gather chains per wave (vs 8 in the slot design) -> latency actually hidden.
// Divergence cost: wave runs to max(cnt) over 32 Poisson(16) segs ~ 26 vs 16.
template <int MODE>
__launch_bounds__(256)
__global__ void agg_planar_kernel(const char* __restrict__ src, const int2* __restrict__ meta,
                                  const int* __restrict__ col, const float* __restrict__ bias,
                                  char* __restrict__ dst) {
    int slice = blockIdx.x & 7;
    int g = blockIdx.x >> 3;
    int tid = threadIdx.x;
    int lane = tid & 63, wid = tid >> 6;
    int half = lane & 1;
    int seg = g * 128 + (tid >> 1);
    bool segok = seg < N_NODES;
    const char* plane = src + (size_t)slice * PLANE_BYTES;

    float b8[8];
    if constexpr (MODE >= 1) {
        const float4* b4 = (const float4*)(bias + slice * 16 + half * 8);
        float4 lo = b4[0], hi = b4[1];
        b8[0] = lo.x; b8[1] = lo.y; b8[2] = lo.z; b8[3] = lo.w;
        b8[4] = hi.x; b8[5] = hi.y; b8[6] = hi.z; b8[7] = hi.w;
    }

    // meta is allocated NBUCK*B_KEYS = 100352 entries >= max seg 100095
    int2 mt = meta[seg];
    int s = mt.x;
    int cnt = segok ? mt.y : 0;
    const int* cp = col + s;

    float acc[8] = {0.f, 0.f, 0.f, 0.f, 0.f, 0.f, 0.f, 0.f};
    int j = 0;
    int idxc = cp[0];                       // prefetch (valid memory even if cnt==0)
    while (__any(j < cnt)) {
        int jn = j + 1;
        int jcl = (jn < cnt) ? jn : 0;      // clamp keeps reads inside this segment
        int idxn = cp[jcl];                 // next-index prefetch (off the gather recurrence)
        float msk = (j < cnt) ? 1.0f : 0.0f;
        uint4 u = *(const uint4*)(plane + (size_t)idxc * 32 + half * 16);
        acc8_fma(acc, u, msk);
        idxc = idxn;
        j = jn;
    }

    float sc = cnt ? 1.0f / (float)cnt : 0.0f;
    if constexpr (MODE == 0) {
        if (segok) {
            uint4 o;
            o.x = packbf2(acc[0] * sc, acc[1] * sc);
            o.y = packbf2(acc[2] * sc, acc[3] * sc);
            o.z = packbf2(acc[4] * sc, acc[5] * sc);
            o.w = packbf2(acc[6] * sc, acc[7] * sc);
            *(uint4*)(dst + (size_t)slice * PLANE_BYTES + (size_t)seg * 32 + half * 16) = o;
        }
    } else if constexpr (MODE == 1) {
        if (segok) {
            uint4 o;
            o.x = packbf2(fmaxf(fmaf(acc[0], sc, b8[0]), 0.f), fmaxf(fmaf(acc[1], sc, b8[1]), 0.f));
            o.y = packbf2(fmaxf(fmaf(acc[2], sc, b8[2]), 0.f), fmaxf(fmaf(acc[3], sc, b8[3]), 0.f));
            o.z = packbf2(fmaxf(fmaf(acc[4], sc, b8[4]), 0.f), fmaxf(fmaf(acc[5], sc, b8[5]), 0.f));
            o.w = packbf2(fmaxf(fmaf(acc[6], sc, b8[6]), 0.f), fmaxf(fmaf(acc[7], sc, b8[7]), 0.f));
            *(uint4*)(dst + (size_t)slice * PLANE_BYTES + (size_t)seg * 32 + half * 16) = o;
        }
    } else {
        // relu(acc*sc + b) for real segs; reduce over the 32 segs in this wave
        float v8[8];
#pragma unroll
        for (int i = 0; i < 8; ++i)
            v8[i] = segok ? fmaxf(fmaf(acc[i], sc, b8[i]), 0.f) : 0.f;
#pragma unroll
        for (int i = 0; i < 8; ++i) {
            v8[i] += __shfl_xor(v8[i], 2);
            v8[i] += __shfl_xor(v8[i], 4);
            v8[i] += __shfl_xor(v8[i], 8);
            v8[i] += __shfl_xor(v8[i], 16);
            v8[i] += __shfl_xor(v8[i], 32);
        }
        __shared__ float sp[4][16];
        if (lane < 2) {
#pragma unroll
            for (int i = 0; i < 8; ++i) sp[wid][half * 8 + i] = v8[i];
        }
        __syncthreads();
        if (tid < 16) {
            float r = sp[0][tid] + sp[1][tid] + sp[2][tid] + sp[3][tid];
            ((float*)dst)[((size_t)slice * GBLK + g) * 16 + tid] = r;
        }
    }
}

// ---------------- mean: reduce per-block partials [8][GBLK][16] ----------------
__launch_bounds__(256)
__global__ void mean_kernel(const float* __restrict__ partials, float* __restrict__ out) {
    __shared__ float sd[256];
    int f = blockIdx.x;               // 0..127
    int slice = f >> 4, w = f & 15;
    float s = 0.f;
    for (int g = threadIdx.x; g < GBLK; g += 256)
        s += partials[((size_t)slice * GBLK + g) * 16 + w];
    sd[threadIdx.x] = s;
    __syncthreads();
#pragma unroll
    for (int o = 128; o > 0; o >>= 1) {
        if (threadIdx.x < o) sd[threadIdx.x] += sd[threadIdx.x + o];
        __syncthreads();
    }
    if (threadIdx.x == 0) out[f] = sd[0] * (1.0f / (float)N_NODES);
}

// ---------------- launch ----------------
extern "C" void kernel_launch(void* const* d_in, const int* in_sizes, int n_in,
                              void* d_out, int out_size, void* d_ws, size_t ws_size,
                              hipStream_t stream) {
    const float* x  = (const float*)d_in[0];
    const int*   ei = (const int*)d_in[1];
    const float* w1 = (const float*)d_in[2];
    const float* b1 = (const float*)d_in[3];
    const float* w2 = (const float*)d_in[4];
    const float* b2 = (const float*)d_in[5];
    float* out = (float*)d_out;
    const int* nidx = ei;
    const int* hidx = ei + N_INC;

    char* wsp = (char*)d_ws;
    size_t off = 0;
    auto alloc = [&](size_t bytes) -> void* {
        void* p = wsp + off;
        off += (bytes + 255) & ~(size_t)255;
        return p;
    };

    char* B0         = (char*)alloc((size_t)N_NODES * 128 * 2);   // planar bf16
    char* B1         = (char*)alloc((size_t)N_NODES * 128 * 2);   // planar bf16
    unsigned* bin_e  = (unsigned*)alloc((size_t)NBUCK * CAP * 4);
    unsigned* bin_n  = (unsigned*)alloc((size_t)NBUCK * CAP * 4);
    int* csr_e       = (int*)alloc((size_t)NBUCK * CAP * 4);
    int* csr_n       = (int*)alloc((size_t)NBUCK * CAP * 4);
    float* partials  = (float*)alloc((size_t)NSLICE * GBLK * 16 * 4);
    int2* meta_e     = (int2*)alloc((size_t)NBUCK * B_KEYS * 8);
    int2* meta_n     = (int2*)alloc((size_t)NBUCK * B_KEYS * 8);
    short* WT1       = (short*)alloc((size_t)128 * 128 * 2);
    short* WT2       = (short*)alloc((size_t)128 * 128 * 2);
    int* gcnt        = (int*)alloc((size_t)2 * NBUCK * 4);
    int* gcnt_e = gcnt;
    int* gcnt_n = gcnt + NBUCK;

    wt_kernel<<<128, 256, 0, stream>>>(w1, w2, WT1, WT2, gcnt);
    binA_kernel<<<NBLKA, 256, 0, stream>>>(nidx, hidx, gcnt_e, gcnt_n, bin_e, bin_n);
    binB2_kernel<<<2 * NBUCK, 512, 0, stream>>>(gcnt_e, bin_e, csr_e, meta_e,
                                                gcnt_n, bin_n, csr_n, meta_n);

    int gGemm = (N_NODES + 63) / 64;
    int gAgg = NSLICE * GBLK;

    // layer 1
    gemm_mfma_kernel<false><<<gGemm, 256, 0, stream>>>(x, WT1, B0, N_NODES);
    agg_planar_kernel<0><<<gAgg, 256, 0, stream>>>(B0, meta_e, csr_e, nullptr, B1);
    agg_planar_kernel<1><<<gAgg, 256, 0, stream>>>(B1, meta_n, csr_n, b1, B0);
    // layer 2
    gemm_mfma_kernel<true><<<gGemm, 256, 0, stream>>>(B0, WT2, B1, N_NODES);
    agg_planar_kernel<0><<<gAgg, 256, 0, stream>>>(B1, meta_e, csr_e, nullptr, B0);
    agg_planar_kernel<2><<<gAgg, 256, 0, stream>>>(B0, meta_n, csr_n, b2, (char*)partials);
    mean_kernel<<<128, 256, 0, stream>>>(partials, out);
}

// Round 4
// 493.044 us; speedup vs baseline: 1.8269x; 1.8269x over previous
//
#include <hip/hip_runtime.h>
#include <hip/hip_bf16.h>

#define N_NODES 100000
#define N_HEDGES 100000
#define N_INC 1600000
#define D 128

#define B_KEYS 512            // keys per bucket
#define NBUCK 196             // ceil(100000/512)
#define CAP 10240             // bucket capacity (mean 8192, sigma ~90)
#define CHUNK 4096            // 16 items per thread, register-resident
#define NBLKA ((N_INC + CHUNK - 1) / CHUNK)   // 391

#define LDA 136               // padded bf16 row stride for GEMM LDS tiles

// ---- feature-sliced planar layout: 8 planes of 16 features (32 B) ----
// plane s is a contiguous 3.2 MB region -> L2-resident on the XCD that owns
// slice s (blockIdx & 7 ~ XCD round-robin). Round-1/2 proof: FETCH_SIZE
// dropped 181 MB -> 43 MB (= index stream only) when index lines die fast.
// Round-3 lesson: 32 live per-lane col streams/wave = 4 MB of live index
// lines per XCD -> plane evicted, FETCH 525 MB. Index data must be staged
// through LDS (coalesced, touched once).
#define NSLICE 8
#define PLANE_SHORTS ((size_t)N_NODES * 16)
#define PLANE_BYTES  ((size_t)N_NODES * 32)
#define GBLK 782              // ceil(100000 / 128) segment groups
#define LDSCOL 3072           // per-block staged index capacity (mean 2048, +22 sigma)

typedef __attribute__((ext_vector_type(8))) short bf16x8;
typedef __attribute__((ext_vector_type(4))) float f32x4;

__device__ __forceinline__ short f2bf(float v) {
    __hip_bfloat16 b = __float2bfloat16(v);
    return *(short*)&b;
}
__device__ __forceinline__ unsigned packbf2(float x, float y) {
    __hip_bfloat162 p = __float22bfloat162_rn(make_float2(x, y));
    return *(unsigned*)&p;
}

// ---------------- W transpose + bf16 convert (once per call) ----------------
__global__ void wt_kernel(const float* __restrict__ W1, const float* __restrict__ W2,
                          short* __restrict__ WT1, short* __restrict__ WT2,
                          int* __restrict__ gcnt) {
    if (blockIdx.x == 0) {
        for (int i = threadIdx.x; i < 2 * NBUCK; i += 256) gcnt[i] = 0;
    }
    int idx = blockIdx.x * 256 + threadIdx.x;     // 0..32767
    int sel = idx >> 14;
    int li = idx & 16383;
    int n = li >> 7, k = li & 127;
    const float* src = sel ? W2 : W1;
    short* dst = sel ? WT2 : WT1;
    dst[li] = f2bf(src[k * 128 + n]);
}

// ---------------- Phase A: bucket partition, register-resident chunk ----------------
__launch_bounds__(256)
__global__ void binA_kernel(const int* __restrict__ nidx, const int* __restrict__ hidx,
                            int* __restrict__ gcnt_e, int* __restrict__ gcnt_n,
                            unsigned* __restrict__ bin_e, unsigned* __restrict__ bin_n) {
    __shared__ int hist_e[NBUCK], hist_n[NBUCK], base_e[NBUCK], base_n[NBUCK];
    int t = threadIdx.x;
    int items_h[16], items_n[16];
    int start = blockIdx.x * CHUNK;
#pragma unroll
    for (int k = 0; k < 16; ++k) {
        int i = start + t + k * 256;
        bool ok = i < N_INC;
        items_h[k] = ok ? hidx[i] : -1;
        items_n[k] = ok ? nidx[i] : -1;
    }
    for (int b = t; b < NBUCK; b += 256) { hist_e[b] = 0; hist_n[b] = 0; }
    __syncthreads();
#pragma unroll
    for (int k = 0; k < 16; ++k) {
        if (items_h[k] >= 0) {
            atomicAdd(&hist_e[items_h[k] >> 9], 1);
            atomicAdd(&hist_n[items_n[k] >> 9], 1);
        }
    }
    __syncthreads();
    for (int b = t; b < NBUCK; b += 256) {
        base_e[b] = atomicAdd(&gcnt_e[b], hist_e[b]);
        base_n[b] = atomicAdd(&gcnt_n[b], hist_n[b]);
        hist_e[b] = 0; hist_n[b] = 0;
    }
    __syncthreads();
#pragma unroll
    for (int k = 0; k < 16; ++k) {
        if (items_h[k] >= 0) {
            int h = items_h[k], n = items_n[k];
            int be = h >> 9, bn = n >> 9;
            int oe = base_e[be] + atomicAdd(&hist_e[be], 1);
            if (oe >= 0 && oe < CAP) bin_e[(size_t)be * CAP + oe] = ((unsigned)(h & 511) << 17) | (unsigned)n;
            int on = base_n[bn] + atomicAdd(&hist_n[bn], 1);
            if (on >= 0 && on < CAP) bin_n[(size_t)bn * CAP + on] = ((unsigned)(n & 511) << 17) | (unsigned)h;
        }
    }
}

// ---------------- Phase B: per-bucket counting sort, wave-shuffle scan ----------
__launch_bounds__(512)
__global__ void binB2_kernel(const int* __restrict__ gcnt_e, const unsigned* __restrict__ bin_e,
                             int* __restrict__ csr_e, int2* __restrict__ meta_e,
                             const int* __restrict__ gcnt_n, const unsigned* __restrict__ bin_n,
                             int* __restrict__ csr_n, int2* __restrict__ meta_n) {
    __shared__ int kc[B_KEYS];
    __shared__ int wsum[8];
    int b = blockIdx.x;
    const int* gcnt;  const unsigned* bin;  int* csr;  int2* meta;
    if (b < NBUCK) { gcnt = gcnt_e; bin = bin_e; csr = csr_e; meta = meta_e; }
    else { b -= NBUCK; gcnt = gcnt_n; bin = bin_n; csr = csr_n; meta = meta_n; }
    int t = threadIdx.x;
    int lane = t & 63, wv = t >> 6;
    int cnt = gcnt[b];
    if (cnt > CAP) cnt = CAP;
    kc[t] = 0;
    __syncthreads();
    const unsigned* items = bin + (size_t)b * CAP;
    for (int i = t; i < cnt; i += 512) atomicAdd(&kc[items[i] >> 17], 1);
    __syncthreads();
    int mycnt = kc[t];
    int v = mycnt;
#pragma unroll
    for (int off = 1; off < 64; off <<= 1) {
        int u = __shfl_up(v, off);
        if (lane >= off) v += u;
    }
    if (lane == 63) wsum[wv] = v;
    __syncthreads();
    int addp = 0;
#pragma unroll
    for (int w = 0; w < 7; ++w) addp += (w < wv) ? wsum[w] : 0;
    int incl = v + addp;
    int sstart = b * CAP + (incl - mycnt);   // exclusive start
    meta[b * B_KEYS + t] = make_int2(sstart, mycnt);
    kc[t] = sstart;
    __syncthreads();
    for (int i = t; i < cnt; i += 512) {
        unsigned it = items[i];
        int pos = atomicAdd(&kc[it >> 17], 1);
        csr[pos] = (int)(it & 0x1FFFFu);
    }
}

// ---------------- MFMA bf16 GEMM: planar output [8][N][16 feats] ----------------
template <bool PLANAR>
__launch_bounds__(256)
__global__ void gemm_mfma_kernel(const void* __restrict__ Xv, const short* __restrict__ WT,
                                 char* __restrict__ Y, int nrows) {
    __shared__ short lds_w[128 * LDA];   // W^T [n][k]; later reused for C staging
    int tid = threadIdx.x;
    int row0 = blockIdx.x * 64;

    {
        const uint4* w4 = (const uint4*)WT;
#pragma unroll
        for (int i = 0; i < 8; ++i) {
            int idx = tid + i * 256;          // 0..2047 = 128 rows x 16 uint4
            int n = idx >> 4, g = idx & 15;
            *(uint4*)(lds_w + n * LDA + g * 8) = w4[idx];
        }
    }

    int wv = tid >> 6, lane = tid & 63;
    int m = lane & 15, quad = lane >> 4;
    int row = row0 + wv * 16 + m;
    bool rowok = row < nrows;

    bf16x8 af[4];
    if constexpr (!PLANAR) {
        const float* xr = (const float*)Xv + (size_t)row * 128 + quad * 8;
#pragma unroll
        for (int k0 = 0; k0 < 4; ++k0) {
            float4 a0 = make_float4(0.f, 0.f, 0.f, 0.f), a1 = a0;
            if (rowok) {
                a0 = *(const float4*)(xr + k0 * 32);
                a1 = *(const float4*)(xr + k0 * 32 + 4);
            }
            bf16x8 f;
            f[0] = f2bf(a0.x); f[1] = f2bf(a0.y); f[2] = f2bf(a0.z); f[3] = f2bf(a0.w);
            f[4] = f2bf(a1.x); f[5] = f2bf(a1.y); f[6] = f2bf(a1.z); f[7] = f2bf(a1.w);
            af[k0] = f;
        }
    } else {
        const short* X = (const short*)Xv;
#pragma unroll
        for (int k0 = 0; k0 < 4; ++k0) {
            int p = k0 * 2 + (quad >> 1);
            bf16x8 f = {0, 0, 0, 0, 0, 0, 0, 0};
            if (rowok) f = *(const bf16x8*)(X + (size_t)p * PLANE_SHORTS + (size_t)row * 16 + (quad & 1) * 8);
            af[k0] = f;
        }
    }
    __syncthreads();   // W staged

    f32x4 zero = {0.f, 0.f, 0.f, 0.f};
    f32x4 acc[8];
#pragma unroll
    for (int t8 = 0; t8 < 8; ++t8) acc[t8] = zero;

#pragma unroll
    for (int t8 = 0; t8 < 8; ++t8) {
        const short* brow = lds_w + (t8 * 16 + m) * LDA + quad * 8;
#pragma unroll
        for (int k0 = 0; k0 < 4; ++k0) {
            bf16x8 bf = *(const bf16x8*)(brow + k0 * 32);
            acc[t8] = __builtin_amdgcn_mfma_f32_16x16x32_bf16(af[k0], bf, acc[t8], 0, 0, 0);
        }
    }

    __syncthreads();   // all W ds_reads done; reuse lds_w for C staging
    // C/D layout: col = lane&15, row = quad*4 + reg
#pragma unroll
    for (int t8 = 0; t8 < 8; ++t8) {
#pragma unroll
        for (int r = 0; r < 4; ++r) {
            int crow = wv * 16 + quad * 4 + r;
            int col = t8 * 16 + m;
            lds_w[crow * LDA + col] = f2bf(acc[t8][r]);
        }
    }
    __syncthreads();
    // planar store: per wave one plane, 64 rows x 2 halves = 1 KB contiguous
#pragma unroll
    for (int i = 0; i < 4; ++i) {
        int idx = tid + i * 256;              // 0..1023
        int slice = idx >> 7, j = idx & 127;  // j = row*2 + half
        int r = j >> 1, h = j & 1;
        if (row0 + r < nrows) {
            uint4 u = *(const uint4*)(lds_w + r * LDA + slice * 16 + h * 8);
            *(uint4*)(Y + (size_t)slice * PLANE_BYTES + (size_t)(row0 + r) * 32 + h * 16) = u;
        }
    }
}

// ---------------- lane-owns-segment gather-sum, LDS-staged indices ----------------
__device__ __forceinline__ void acc8_fma(float* a, uint4 u, float msk) {
    a[0] = fmaf(msk, __uint_as_float(u.x << 16), a[0]);
    a[1] = fmaf(msk, __uint_as_float(u.x & 0xFFFF0000u), a[1]);
    a[2] = fmaf(msk, __uint_as_float(u.y << 16), a[2]);
    a[3] = fmaf(msk, __uint_as_float(u.y & 0xFFFF0000u), a[3]);
    a[4] = fmaf(msk, __uint_as_float(u.z << 16), a[4]);
    a[5] = fmaf(msk, __uint_as_float(u.z & 0xFFFF0000u), a[5]);
    a[6] = fmaf(msk, __uint_as_float(u.w << 16), a[6]);
    a[7] = fmaf(msk, __uint_as_float(u.w & 0xFFFF0000u), a[7]);
}

// MODE 0: edge agg (scale only, planar bf16 out)
// MODE 1: node agg + bias + relu (planar bf16 out)
// MODE 2: node agg + bias + relu -> per-block 16-col partials (dst = float*)
//
// Structure: 2 lanes per segment (one 16 B half each), 32 segs/wave, 128/block.
// A block's 128 segments are consecutive within ONE bucket (512 % 128 == 0),
// so their CSR index data is one contiguous run of col[] -> stage it to LDS
// coalesced (touched once, lines die -> plane stays L2-resident), then each
// lane walks its segment from LDS with 2-deep unrolled gathers.
template <int MODE>
__launch_bounds__(256)
__global__ void agg_planar_kernel(const char* __restrict__ src, const int2* __restrict__ meta,
                                  const int* __restrict__ col, const float* __restrict__ bias,
                                  char* __restrict__ dst) {
    __shared__ int lds_col[LDSCOL];
    int slice = blockIdx.x & 7;
    int g = blockIdx.x >> 3;
    int tid = threadIdx.x;
    int lane = tid & 63, wid = tid >> 6;
    int half = tid & 1;
    int seg = g * 128 + (tid >> 1);
    bool segok = seg < N_NODES;
    const char* plane = src + (size_t)slice * PLANE_BYTES;

    // block-contiguous CSR range [r0, r0+total)
    int gbase = g * 128;
    int2 mF = meta[gbase];            // uniform address -> scalar load
    int2 mL = meta[gbase + 127];
    int r0 = mF.x;
    int total = mL.x + mL.y - r0;
    if (total > LDSCOL) total = LDSCOL;   // +22 sigma, never in practice

    // zero-fill then real fill: thread t owns slots i == t (mod 256) in both
    // loops -> no race, single barrier below.
#pragma unroll
    for (int i = 0; i < LDSCOL / 256; ++i) lds_col[tid + i * 256] = 0;
    for (int i = tid; i < total; i += 256) lds_col[i] = col[r0 + i];

    float b8[8];
    if constexpr (MODE >= 1) {
        const float4* b4 = (const float4*)(bias + slice * 16 + half * 8);
        float4 lo = b4[0], hi = b4[1];
        b8[0] = lo.x; b8[1] = lo.y; b8[2] = lo.z; b8[3] = lo.w;
        b8[4] = hi.x; b8[5] = hi.y; b8[6] = hi.z; b8[7] = hi.w;
    }

    int2 mt = meta[seg];              // meta fully written for all 100352 slots
    int ls = mt.x - r0;
    int cnt = segok ? mt.y : 0;
    if (ls < 0 || ls + cnt > LDSCOL) cnt = 0;   // paranoia with the clamp above
    __syncthreads();

    float acc[8] = {0.f, 0.f, 0.f, 0.f, 0.f, 0.f, 0.f, 0.f};
    int j = 0;
    while (__any(j < cnt)) {
        int a0 = ls + ((j < cnt) ? j : 0);
        int a1 = ls + ((j + 1 < cnt) ? j + 1 : 0);
        int i0 = lds_col[a0];
        int i1 = lds_col[a1];
        float mk0 = (j < cnt) ? 1.0f : 0.0f;
        float mk1 = (j + 1 < cnt) ? 1.0f : 0.0f;
        uint4 u0 = *(const uint4*)(plane + (size_t)i0 * 32 + half * 16);
        uint4 u1 = *(const uint4*)(plane + (size_t)i1 * 32 + half * 16);
        acc8_fma(acc, u0, mk0);
        acc8_fma(acc, u1, mk1);
        j += 2;
    }

    float sc = cnt ? 1.0f / (float)cnt : 0.0f;
    if constexpr (MODE == 0) {
        if (segok) {
            uint4 o;
            o.x = packbf2(acc[0] * sc, acc[1] * sc);
            o.y = packbf2(acc[2] * sc, acc[3] * sc);
            o.z = packbf2(acc[4] * sc, acc[5] * sc);
            o.w = packbf2(acc[6] * sc, acc[7] * sc);
            *(uint4*)(dst + (size_t)slice * PLANE_BYTES + (size_t)seg * 32 + half * 16) = o;
        }
    } else if constexpr (MODE == 1) {
        if (segok) {
            uint4 o;
            o.x = packbf2(fmaxf(fmaf(acc[0], sc, b8[0]), 0.f), fmaxf(fmaf(acc[1], sc, b8[1]), 0.f));
            o.y = packbf2(fmaxf(fmaf(acc[2], sc, b8[2]), 0.f), fmaxf(fmaf(acc[3], sc, b8[3]), 0.f));
            o.z = packbf2(fmaxf(fmaf(acc[4], sc, b8[4]), 0.f), fmaxf(fmaf(acc[5], sc, b8[5]), 0.f));
            o.w = packbf2(fmaxf(fmaf(acc[6], sc, b8[6]), 0.f), fmaxf(fmaf(acc[7], sc, b8[7]), 0.f));
            *(uint4*)(dst + (size_t)slice * PLANE_BYTES + (size_t)seg * 32 + half * 16) = o;
        }
    } else {
        // relu(acc*sc + b) for real segs; reduce over 32 segs in wave, 4 waves
        float v8[8];
#pragma unroll
        for (int i = 0; i < 8; ++i)
            v8[i] = segok ? fmaxf(fmaf(acc[i], sc, b8[i]), 0.f) : 0.f;
#pragma unroll
        for (int i = 0; i < 8; ++i) {
            v8[i] += __shfl_xor(v8[i], 2);
            v8[i] += __shfl_xor(v8[i], 4);
            v8[i] += __shfl_xor(v8[i], 8);
            v8[i] += __shfl_xor(v8[i], 16);
            v8[i] += __shfl_xor(v8[i], 32);
        }
        __shared__ float sp[4][16];
        if (lane < 2) {
#pragma unroll
            for (int i = 0; i < 8; ++i) sp[wid][half * 8 + i] = v8[i];
        }
        __syncthreads();
        if (tid < 16) {
            float r = sp[0][tid] + sp[1][tid] + sp[2][tid] + sp[3][tid];
            ((float*)dst)[((size_t)slice * GBLK + g) * 16 + tid] = r;
        }
    }
}

// ---------------- mean: reduce per-block partials [8][GBLK][16] ----------------
__launch_bounds__(256)
__global__ void mean_kernel(const float* __restrict__ partials, float* __restrict__ out) {
    __shared__ float sd[256];
    int f = blockIdx.x;               // 0..127
    int slice = f >> 4, w = f & 15;
    float s = 0.f;
    for (int g = threadIdx.x; g < GBLK; g += 256)
        s += partials[((size_t)slice * GBLK + g) * 16 + w];
    sd[threadIdx.x] = s;
    __syncthreads();
#pragma unroll
    for (int o = 128; o > 0; o >>= 1) {
        if (threadIdx.x < o) sd[threadIdx.x] += sd[threadIdx.x + o];
        __syncthreads();
    }
    if (threadIdx.x == 0) out[f] = sd[0] * (1.0f / (float)N_NODES);
}

// ---------------- launch ----------------
extern "C" void kernel_launch(void* const* d_in, const int* in_sizes, int n_in,
                              void* d_out, int out_size, void* d_ws, size_t ws_size,
                              hipStream_t stream) {
    const float* x  = (const float*)d_in[0];
    const int*   ei = (const int*)d_in[1];
    const float* w1 = (const float*)d_in[2];
    const float* b1 = (const float*)d_in[3];
    const float* w2 = (const float*)d_in[4];
    const float* b2 = (const float*)d_in[5];
    float* out = (float*)d_out;
    const int* nidx = ei;
    const int* hidx = ei + N_INC;

    char* wsp = (char*)d_ws;
    size_t off = 0;
    auto alloc = [&](size_t bytes) -> void* {
        void* p = wsp + off;
        off += (bytes + 255) & ~(size_t)255;
        return p;
    };

    char* B0         = (char*)alloc((size_t)N_NODES * 128 * 2);   // planar bf16
    char* B1         = (char*)alloc((size_t)N_NODES * 128 * 2);   // planar bf16
    unsigned* bin_e  = (unsigned*)alloc((size_t)NBUCK * CAP * 4);
    unsigned* bin_n  = (unsigned*)alloc((size_t)NBUCK * CAP * 4);
    int* csr_e       = (int*)alloc((size_t)NBUCK * CAP * 4);
    int* csr_n       = (int*)alloc((size_t)NBUCK * CAP * 4);
    float* partials  = (float*)alloc((size_t)NSLICE * GBLK * 16 * 4);
    int2* meta_e     = (int2*)alloc((size_t)NBUCK * B_KEYS * 8);
    int2* meta_n     = (int2*)alloc((size_t)NBUCK * B_KEYS * 8);
    short* WT1       = (short*)alloc((size_t)128 * 128 * 2);
    short* WT2       = (short*)alloc((size_t)128 * 128 * 2);
    int* gcnt        = (int*)alloc((size_t)2 * NBUCK * 4);
    int* gcnt_e = gcnt;
    int* gcnt_n = gcnt + NBUCK;

    wt_kernel<<<128, 256, 0, stream>>>(w1, w2, WT1, WT2, gcnt);
    binA_kernel<<<NBLKA, 256, 0, stream>>>(nidx, hidx, gcnt_e, gcnt_n, bin_e, bin_n);
    binB2_kernel<<<2 * NBUCK, 512, 0, stream>>>(gcnt_e, bin_e, csr_e, meta_e,
                                                gcnt_n, bin_n, csr_n, meta_n);

    int gGemm = (N_NODES + 63) / 64;
    int gAgg = NSLICE * GBLK;

    // layer 1
    gemm_mfma_kernel<false><<<gGemm, 256, 0, stream>>>(x, WT1, B0, N_NODES);
    agg_planar_kernel<0><<<gAgg, 256, 0, stream>>>(B0, meta_e, csr_e, nullptr, B1);
    agg_planar_kernel<1><<<gAgg, 256, 0, stream>>>(B1, meta_n, csr_n, b1, B0);
    // layer 2
    gemm_mfma_kernel<true><<<gGemm, 256, 0, stream>>>(B0, WT2, B1, N_NODES);
    agg_planar_kernel<0><<<gAgg, 256, 0, stream>>>(B1, meta_e, csr_e, nullptr, B0);
    agg_planar_kernel<2><<<gAgg, 256, 0, stream>>>(B0, meta_n, csr_n, b2, (char*)partials);
    mean_kernel<<<128, 256, 0, stream>>>(partials, out);
}

// Round 5
// 429.562 us; speedup vs baseline: 2.0969x; 1.1478x over previous
//
#include <hip/hip_runtime.h>
#include <hip/hip_bf16.h>

#define N_NODES 100000
#define N_HEDGES 100000
#define N_INC 1600000
#define D 128

#define B_KEYS 512            // keys per bucket
#define NBUCK 196             // ceil(100000/512)
#define CAP 10240             // bucket capacity (mean 8192, sigma ~90)
#define CHUNK 4096            // 16 items per thread, register-resident
#define NBLKA ((N_INC + CHUNK - 1) / CHUNK)   // 391

#define LDA 136               // padded bf16 row stride for GEMM LDS tiles

// ---- feature-sliced planar layout: 8 planes of 16 features (32 B) ----
// plane s is a contiguous 3.2 MB region -> L2-resident on the XCD that owns
// slice s (blockIdx & 7 ~ XCD round-robin). FETCH floor = col stream (~48 MB).
// Round-4 lesson: 32-B row gathers through L1 fill 128-B lines (4x L2->L1
// amplification, ~2.8 GB/pass = the 87 us). Fix: sc0 (SE-scope) buffer loads
// bypass L1 -> exact 32-B granules from L2; exec-masked divergence instead of
// __any+mask kills the 1.7x wasted-transaction factor.
#define NSLICE 8
#define PLANE_SHORTS ((size_t)N_NODES * 16)
#define PLANE_BYTES  ((size_t)N_NODES * 32)
#define GBLK 782              // ceil(100000 / 128) segment groups
#define LDSCOL 3072           // per-block staged index capacity (mean 2048, +22 sigma)

typedef __attribute__((ext_vector_type(8))) short bf16x8;
typedef __attribute__((ext_vector_type(4))) float f32x4;
typedef __attribute__((ext_vector_type(4))) unsigned uint4v;

__device__ __forceinline__ short f2bf(float v) {
    __hip_bfloat16 b = __float2bfloat16(v);
    return *(short*)&b;
}
__device__ __forceinline__ unsigned packbf2(float x, float y) {
    __hip_bfloat162 p = __float22bfloat162_rn(make_float2(x, y));
    return *(unsigned*)&p;
}

// ---------------- W transpose + bf16 convert (once per call) ----------------
__global__ void wt_kernel(const float* __restrict__ W1, const float* __restrict__ W2,
                          short* __restrict__ WT1, short* __restrict__ WT2,
                          int* __restrict__ gcnt) {
    if (blockIdx.x == 0) {
        for (int i = threadIdx.x; i < 2 * NBUCK; i += 256) gcnt[i] = 0;
    }
    int idx = blockIdx.x * 256 + threadIdx.x;     // 0..32767
    int sel = idx >> 14;
    int li = idx & 16383;
    int n = li >> 7, k = li & 127;
    const float* src = sel ? W2 : W1;
    short* dst = sel ? WT2 : WT1;
    dst[li] = f2bf(src[k * 128 + n]);
}

// ---------------- Phase A: bucket partition, register-resident chunk ----------------
__launch_bounds__(256)
__global__ void binA_kernel(const int* __restrict__ nidx, const int* __restrict__ hidx,
                            int* __restrict__ gcnt_e, int* __restrict__ gcnt_n,
                            unsigned* __restrict__ bin_e, unsigned* __restrict__ bin_n) {
    __shared__ int hist_e[NBUCK], hist_n[NBUCK], base_e[NBUCK], base_n[NBUCK];
    int t = threadIdx.x;
    int items_h[16], items_n[16];
    int start = blockIdx.x * CHUNK;
#pragma unroll
    for (int k = 0; k < 16; ++k) {
        int i = start + t + k * 256;
        bool ok = i < N_INC;
        items_h[k] = ok ? hidx[i] : -1;
        items_n[k] = ok ? nidx[i] : -1;
    }
    for (int b = t; b < NBUCK; b += 256) { hist_e[b] = 0; hist_n[b] = 0; }
    __syncthreads();
#pragma unroll
    for (int k = 0; k < 16; ++k) {
        if (items_h[k] >= 0) {
            atomicAdd(&hist_e[items_h[k] >> 9], 1);
            atomicAdd(&hist_n[items_n[k] >> 9], 1);
        }
    }
    __syncthreads();
    for (int b = t; b < NBUCK; b += 256) {
        base_e[b] = atomicAdd(&gcnt_e[b], hist_e[b]);
        base_n[b] = atomicAdd(&gcnt_n[b], hist_n[b]);
        hist_e[b] = 0; hist_n[b] = 0;
    }
    __syncthreads();
#pragma unroll
    for (int k = 0; k < 16; ++k) {
        if (items_h[k] >= 0) {
            int h = items_h[k], n = items_n[k];
            int be = h >> 9, bn = n >> 9;
            int oe = base_e[be] + atomicAdd(&hist_e[be], 1);
            if (oe >= 0 && oe < CAP) bin_e[(size_t)be * CAP + oe] = ((unsigned)(h & 511) << 17) | (unsigned)n;
            int on = base_n[bn] + atomicAdd(&hist_n[bn], 1);
            if (on >= 0 && on < CAP) bin_n[(size_t)bn * CAP + on] = ((unsigned)(n & 511) << 17) | (unsigned)h;
        }
    }
}

// ---------------- Phase B: per-bucket counting sort, wave-shuffle scan ----------
__launch_bounds__(512)
__global__ void binB2_kernel(const int* __restrict__ gcnt_e, const unsigned* __restrict__ bin_e,
                             int* __restrict__ csr_e, int2* __restrict__ meta_e,
                             const int* __restrict__ gcnt_n, const unsigned* __restrict__ bin_n,
                             int* __restrict__ csr_n, int2* __restrict__ meta_n) {
    __shared__ int kc[B_KEYS];
    __shared__ int wsum[8];
    int b = blockIdx.x;
    const int* gcnt;  const unsigned* bin;  int* csr;  int2* meta;
    if (b < NBUCK) { gcnt = gcnt_e; bin = bin_e; csr = csr_e; meta = meta_e; }
    else { b -= NBUCK; gcnt = gcnt_n; bin = bin_n; csr = csr_n; meta = meta_n; }
    int t = threadIdx.x;
    int lane = t & 63, wv = t >> 6;
    int cnt = gcnt[b];
    if (cnt > CAP) cnt = CAP;
    kc[t] = 0;
    __syncthreads();
    const unsigned* items = bin + (size_t)b * CAP;
    for (int i = t; i < cnt; i += 512) atomicAdd(&kc[items[i] >> 17], 1);
    __syncthreads();
    int mycnt = kc[t];
    int v = mycnt;
#pragma unroll
    for (int off = 1; off < 64; off <<= 1) {
        int u = __shfl_up(v, off);
        if (lane >= off) v += u;
    }
    if (lane == 63) wsum[wv] = v;
    __syncthreads();
    int addp = 0;
#pragma unroll
    for (int w = 0; w < 7; ++w) addp += (w < wv) ? wsum[w] : 0;
    int incl = v + addp;
    int sstart = b * CAP + (incl - mycnt);   // exclusive start
    meta[b * B_KEYS + t] = make_int2(sstart, mycnt);
    kc[t] = sstart;
    __syncthreads();
    for (int i = t; i < cnt; i += 512) {
        unsigned it = items[i];
        int pos = atomicAdd(&kc[it >> 17], 1);
        csr[pos] = (int)(it & 0x1FFFFu);
    }
}

// ---------------- MFMA bf16 GEMM: planar output [8][N][16 feats] ----------------
template <bool PLANAR>
__launch_bounds__(256)
__global__ void gemm_mfma_kernel(const void* __restrict__ Xv, const short* __restrict__ WT,
                                 char* __restrict__ Y, int nrows) {
    __shared__ short lds_w[128 * LDA];   // W^T [n][k]; later reused for C staging
    int tid = threadIdx.x;
    int row0 = blockIdx.x * 64;

    {
        const uint4* w4 = (const uint4*)WT;
#pragma unroll
        for (int i = 0; i < 8; ++i) {
            int idx = tid + i * 256;          // 0..2047 = 128 rows x 16 uint4
            int n = idx >> 4, g = idx & 15;
            *(uint4*)(lds_w + n * LDA + g * 8) = w4[idx];
        }
    }

    int wv = tid >> 6, lane = tid & 63;
    int m = lane & 15, quad = lane >> 4;
    int row = row0 + wv * 16 + m;
    bool rowok = row < nrows;

    bf16x8 af[4];
    if constexpr (!PLANAR) {
        const float* xr = (const float*)Xv + (size_t)row * 128 + quad * 8;
#pragma unroll
        for (int k0 = 0; k0 < 4; ++k0) {
            float4 a0 = make_float4(0.f, 0.f, 0.f, 0.f), a1 = a0;
            if (rowok) {
                a0 = *(const float4*)(xr + k0 * 32);
                a1 = *(const float4*)(xr + k0 * 32 + 4);
            }
            bf16x8 f;
            f[0] = f2bf(a0.x); f[1] = f2bf(a0.y); f[2] = f2bf(a0.z); f[3] = f2bf(a0.w);
            f[4] = f2bf(a1.x); f[5] = f2bf(a1.y); f[6] = f2bf(a1.z); f[7] = f2bf(a1.w);
            af[k0] = f;
        }
    } else {
        const short* X = (const short*)Xv;
#pragma unroll
        for (int k0 = 0; k0 < 4; ++k0) {
            int p = k0 * 2 + (quad >> 1);
            bf16x8 f = {0, 0, 0, 0, 0, 0, 0, 0};
            if (rowok) f = *(const bf16x8*)(X + (size_t)p * PLANE_SHORTS + (size_t)row * 16 + (quad & 1) * 8);
            af[k0] = f;
        }
    }
    __syncthreads();   // W staged

    f32x4 zero = {0.f, 0.f, 0.f, 0.f};
    f32x4 acc[8];
#pragma unroll
    for (int t8 = 0; t8 < 8; ++t8) acc[t8] = zero;

#pragma unroll
    for (int t8 = 0; t8 < 8; ++t8) {
        const short* brow = lds_w + (t8 * 16 + m) * LDA + quad * 8;
#pragma unroll
        for (int k0 = 0; k0 < 4; ++k0) {
            bf16x8 bf = *(const bf16x8*)(brow + k0 * 32);
            acc[t8] = __builtin_amdgcn_mfma_f32_16x16x32_bf16(af[k0], bf, acc[t8], 0, 0, 0);
        }
    }

    __syncthreads();   // all W ds_reads done; reuse lds_w for C staging
    // C/D layout: col = lane&15, row = quad*4 + reg
#pragma unroll
    for (int t8 = 0; t8 < 8; ++t8) {
#pragma unroll
        for (int r = 0; r < 4; ++r) {
            int crow = wv * 16 + quad * 4 + r;
            int col = t8 * 16 + m;
            lds_w[crow * LDA + col] = f2bf(acc[t8][r]);
        }
    }
    __syncthreads();
    // planar store: per wave one plane, 64 rows x 2 halves = 1 KB contiguous
#pragma unroll
    for (int i = 0; i < 4; ++i) {
        int idx = tid + i * 256;              // 0..1023
        int slice = idx >> 7, j = idx & 127;  // j = row*2 + half
        int r = j >> 1, h = j & 1;
        if (row0 + r < nrows) {
            uint4 u = *(const uint4*)(lds_w + r * LDA + slice * 16 + h * 8);
            *(uint4*)(Y + (size_t)slice * PLANE_BYTES + (size_t)(row0 + r) * 32 + h * 16) = u;
        }
    }
}

// ---------------- sc0 (L1-bypass) gather helpers ----------------
__device__ __forceinline__ uint4v srsrc_make(const void* base, unsigned bytes) {
    union { struct { unsigned lo, hi, nrec, flags; } s; uint4v v; } u;
    unsigned long long p = (unsigned long long)base;
    u.s.lo = (unsigned)p;
    u.s.hi = (unsigned)(p >> 32);      // stride = 0
    u.s.nrec = bytes;                  // num_records in bytes
    u.s.flags = 0x00020000u;           // raw dword access
    return u.v;
}
// loads + waitcnt fused in ONE asm block: outputs are architecturally valid
// when the asm ends (no rule-18 hoisting hazard).
__device__ __forceinline__ void gather4_sc0(uint4v rsrc, unsigned o0, unsigned o1,
                                            unsigned o2, unsigned o3,
                                            uint4v& u0, uint4v& u1, uint4v& u2, uint4v& u3) {
    asm volatile("buffer_load_dwordx4 %0, %4, %8, 0 offen sc0\n\t"
                 "buffer_load_dwordx4 %1, %5, %8, 0 offen sc0\n\t"
                 "buffer_load_dwordx4 %2, %6, %8, 0 offen sc0\n\t"
                 "buffer_load_dwordx4 %3, %7, %8, 0 offen sc0\n\t"
                 "s_waitcnt vmcnt(0)"
                 : "=&v"(u0), "=&v"(u1), "=&v"(u2), "=&v"(u3)
                 : "v"(o0), "v"(o1), "v"(o2), "v"(o3), "s"(rsrc));
}
__device__ __forceinline__ void gather2_sc0(uint4v rsrc, unsigned o0, unsigned o1,
                                            uint4v& u0, uint4v& u1) {
    asm volatile("buffer_load_dwordx4 %0, %2, %4, 0 offen sc0\n\t"
                 "buffer_load_dwordx4 %1, %3, %4, 0 offen sc0\n\t"
                 "s_waitcnt vmcnt(0)"
                 : "=&v"(u0), "=&v"(u1)
                 : "v"(o0), "v"(o1), "s"(rsrc));
}
__device__ __forceinline__ void gather1_sc0(uint4v rsrc, unsigned o0, uint4v& u0) {
    asm volatile("buffer_load_dwordx4 %0, %1, %2, 0 offen sc0\n\t"
                 "s_waitcnt vmcnt(0)"
                 : "=&v"(u0)
                 : "v"(o0), "s"(rsrc));
}

__device__ __forceinline__ void acc8_add(float* a, uint4v u) {
    a[0] += __uint_as_float(u[0] << 16); a[1] += __uint_as_float(u[0] & 0xFFFF0000u);
    a[2] += __uint_as_float(u[1] << 16); a[3] += __uint_as_float(u[1] & 0xFFFF0000u);
    a[4] += __uint_as_float(u[2] << 16); a[5] += __uint_as_float(u[2] & 0xFFFF0000u);
    a[6] += __uint_as_float(u[3] << 16); a[7] += __uint_as_float(u[3] & 0xFFFF0000u);
}

// MODE 0: edge agg (scale only, planar bf16 out)
// MODE 1: node agg + bias + relu (planar bf16 out)
// MODE 2: node agg + bias + relu -> per-block 16-col partials (dst = float*)
//
// Structure: 2 lanes per segment (one 16 B half each), 32 segs/wave, 128/block.
// Indices LDS-staged coalesced (touched once -> plane stays L2-resident).
// Gathers: sc0 buffer loads (L1 bypass, exact 32-B L2 granules), 4-deep MLP,
// natural exec-masked divergence (finished lanes stop issuing transactions).
template <int MODE>
__launch_bounds__(256)
__global__ void agg_planar_kernel(const char* __restrict__ src, const int2* __restrict__ meta,
                                  const int* __restrict__ col, const float* __restrict__ bias,
                                  char* __restrict__ dst) {
    __shared__ int lds_col[LDSCOL];
    int slice = blockIdx.x & 7;
    int g = blockIdx.x >> 3;
    int tid = threadIdx.x;
    int lane = tid & 63, wid = tid >> 6;
    int half = tid & 1;
    int seg = g * 128 + (tid >> 1);
    bool segok = seg < N_NODES;
    const char* plane = src + (size_t)slice * PLANE_BYTES;
    uint4v rsrc = srsrc_make(plane, (unsigned)PLANE_BYTES);

    // block-contiguous CSR range [r0, r0+total)
    int gbase = g * 128;
    int2 mF = meta[gbase];            // uniform address -> scalar load
    int2 mL = meta[gbase + 127];
    int r0 = mF.x;
    int total = mL.x + mL.y - r0;
    if (total > LDSCOL) total = LDSCOL;   // +22 sigma, never in practice

#pragma unroll
    for (int i = 0; i < LDSCOL / 256; ++i) lds_col[tid + i * 256] = 0;
    for (int i = tid; i < total; i += 256) lds_col[i] = col[r0 + i];

    float b8[8];
    if constexpr (MODE >= 1) {
        const float4* b4 = (const float4*)(bias + slice * 16 + half * 8);
        float4 lo = b4[0], hi = b4[1];
        b8[0] = lo.x; b8[1] = lo.y; b8[2] = lo.z; b8[3] = lo.w;
        b8[4] = hi.x; b8[5] = hi.y; b8[6] = hi.z; b8[7] = hi.w;
    }

    int2 mt = meta[seg];              // meta fully written for all 100352 slots
    int ls = mt.x - r0;
    int cnt = segok ? mt.y : 0;
    if (ls < 0 || ls + cnt > LDSCOL) cnt = 0;   // paranoia with the clamp above
    __syncthreads();

    float acc[8] = {0.f, 0.f, 0.f, 0.f, 0.f, 0.f, 0.f, 0.f};
    unsigned hoff = (unsigned)half * 16u;
    int j = 0;
    while (j + 4 <= cnt) {            // divergent: exec mask retires done lanes
        unsigned o0 = ((unsigned)lds_col[ls + j]     << 5) + hoff;
        unsigned o1 = ((unsigned)lds_col[ls + j + 1] << 5) + hoff;
        unsigned o2 = ((unsigned)lds_col[ls + j + 2] << 5) + hoff;
        unsigned o3 = ((unsigned)lds_col[ls + j + 3] << 5) + hoff;
        uint4v u0, u1, u2, u3;
        gather4_sc0(rsrc, o0, o1, o2, o3, u0, u1, u2, u3);
        acc8_add(acc, u0);
        acc8_add(acc, u1);
        acc8_add(acc, u2);
        acc8_add(acc, u3);
        j += 4;
    }
    if (j + 2 <= cnt) {
        unsigned o0 = ((unsigned)lds_col[ls + j]     << 5) + hoff;
        unsigned o1 = ((unsigned)lds_col[ls + j + 1] << 5) + hoff;
        uint4v u0, u1;
        gather2_sc0(rsrc, o0, o1, u0, u1);
        acc8_add(acc, u0);
        acc8_add(acc, u1);
        j += 2;
    }
    if (j < cnt) {
        unsigned o0 = ((unsigned)lds_col[ls + j] << 5) + hoff;
        uint4v u0;
        gather1_sc0(rsrc, o0, u0);
        acc8_add(acc, u0);
    }

    float sc = cnt ? 1.0f / (float)cnt : 0.0f;
    if constexpr (MODE == 0) {
        if (segok) {
            uint4 o;
            o.x = packbf2(acc[0] * sc, acc[1] * sc);
            o.y = packbf2(acc[2] * sc, acc[3] * sc);
            o.z = packbf2(acc[4] * sc, acc[5] * sc);
            o.w = packbf2(acc[6] * sc, acc[7] * sc);
            *(uint4*)(dst + (size_t)slice * PLANE_BYTES + (size_t)seg * 32 + half * 16) = o;
        }
    } else if constexpr (MODE == 1) {
        if (segok) {
            uint4 o;
            o.x = packbf2(fmaxf(fmaf(acc[0], sc, b8[0]), 0.f), fmaxf(fmaf(acc[1], sc, b8[1]), 0.f));
            o.y = packbf2(fmaxf(fmaf(acc[2], sc, b8[2]), 0.f), fmaxf(fmaf(acc[3], sc, b8[3]), 0.f));
            o.z = packbf2(fmaxf(fmaf(acc[4], sc, b8[4]), 0.f), fmaxf(fmaf(acc[5], sc, b8[5]), 0.f));
            o.w = packbf2(fmaxf(fmaf(acc[6], sc, b8[6]), 0.f), fmaxf(fmaf(acc[7], sc, b8[7]), 0.f));
            *(uint4*)(dst + (size_t)slice * PLANE_BYTES + (size_t)seg * 32 + half * 16) = o;
        }
    } else {
        // relu(acc*sc + b) for real segs; reduce over 32 segs in wave, 4 waves
        float v8[8];
#pragma unroll
        for (int i = 0; i < 8; ++i)
            v8[i] = segok ? fmaxf(fmaf(acc[i], sc, b8[i]), 0.f) : 0.f;
#pragma unroll
        for (int i = 0; i < 8; ++i) {
            v8[i] += __shfl_xor(v8[i], 2);
            v8[i] += __shfl_xor(v8[i], 4);
            v8[i] += __shfl_xor(v8[i], 8);
            v8[i] += __shfl_xor(v8[i], 16);
            v8[i] += __shfl_xor(v8[i], 32);
        }
        __shared__ float sp[4][16];
        if (lane < 2) {
#pragma unroll
            for (int i = 0; i < 8; ++i) sp[wid][half * 8 + i] = v8[i];
        }
        __syncthreads();
        if (tid < 16) {
            float r = sp[0][tid] + sp[1][tid] + sp[2][tid] + sp[3][tid];
            ((float*)dst)[((size_t)slice * GBLK + g) * 16 + tid] = r;
        }
    }
}

// ---------------- mean: reduce per-block partials [8][GBLK][16] ----------------
__launch_bounds__(256)
__global__ void mean_kernel(const float* __restrict__ partials, float* __restrict__ out) {
    __shared__ float sd[256];
    int f = blockIdx.x;               // 0..127
    int slice = f >> 4, w = f & 15;
    float s = 0.f;
    for (int g = threadIdx.x; g < GBLK; g += 256)
        s += partials[((size_t)slice * GBLK + g) * 16 + w];
    sd[threadIdx.x] = s;
    __syncthreads();
#pragma unroll
    for (int o = 128; o > 0; o >>= 1) {
        if (threadIdx.x < o) sd[threadIdx.x] += sd[threadIdx.x + o];
        __syncthreads();
    }
    if (threadIdx.x == 0) out[f] = sd[0] * (1.0f / (float)N_NODES);
}

// ---------------- launch ----------------
extern "C" void kernel_launch(void* const* d_in, const int* in_sizes, int n_in,
                              void* d_out, int out_size, void* d_ws, size_t ws_size,
                              hipStream_t stream) {
    const float* x  = (const float*)d_in[0];
    const int*   ei = (const int*)d_in[1];
    const float* w1 = (const float*)d_in[2];
    const float* b1 = (const float*)d_in[3];
    const float* w2 = (const float*)d_in[4];
    const float* b2 = (const float*)d_in[5];
    float* out = (float*)d_out;
    const int* nidx = ei;
    const int* hidx = ei + N_INC;

    char* wsp = (char*)d_ws;
    size_t off = 0;
    auto alloc = [&](size_t bytes) -> void* {
        void* p = wsp + off;
        off += (bytes + 255) & ~(size_t)255;
        return p;
    };

    char* B0         = (char*)alloc((size_t)N_NODES * 128 * 2);   // planar bf16
    char* B1         = (char*)alloc((size_t)N_NODES * 128 * 2);   // planar bf16
    unsigned* bin_e  = (unsigned*)alloc((size_t)NBUCK * CAP * 4);
    unsigned* bin_n  = (unsigned*)alloc((size_t)NBUCK * CAP * 4);
    int* csr_e       = (int*)alloc((size_t)NBUCK * CAP * 4);
    int* csr_n       = (int*)alloc((size_t)NBUCK * CAP * 4);
    float* partials  = (float*)alloc((size_t)NSLICE * GBLK * 16 * 4);
    int2* meta_e     = (int2*)alloc((size_t)NBUCK * B_KEYS * 8);
    int2* meta_n     = (int2*)alloc((size_t)NBUCK * B_KEYS * 8);
    short* WT1       = (short*)alloc((size_t)128 * 128 * 2);
    short* WT2       = (short*)alloc((size_t)128 * 128 * 2);
    int* gcnt        = (int*)alloc((size_t)2 * NBUCK * 4);
    int* gcnt_e = gcnt;
    int* gcnt_n = gcnt + NBUCK;

    wt_kernel<<<128, 256, 0, stream>>>(w1, w2, WT1, WT2, gcnt);
    binA_kernel<<<NBLKA, 256, 0, stream>>>(nidx, hidx, gcnt_e, gcnt_n, bin_e, bin_n);
    binB2_kernel<<<2 * NBUCK, 512, 0, stream>>>(gcnt_e, bin_e, csr_e, meta_e,
                                                gcnt_n, bin_n, csr_n, meta_n);

    int gGemm = (N_NODES + 63) / 64;
    int gAgg = NSLICE * GBLK;

    // layer 1
    gemm_mfma_kernel<false><<<gGemm, 256, 0, stream>>>(x, WT1, B0, N_NODES);
    agg_planar_kernel<0><<<gAgg, 256, 0, stream>>>(B0, meta_e, csr_e, nullptr, B1);
    agg_planar_kernel<1><<<gAgg, 256, 0, stream>>>(B1, meta_n, csr_n, b1, B0);
    // layer 2
    gemm_mfma_kernel<true><<<gGemm, 256, 0, stream>>>(B0, WT2, B1, N_NODES);
    agg_planar_kernel<0><<<gAgg, 256, 0, stream>>>(B1, meta_e, csr_e, nullptr, B0);
    agg_planar_kernel<2><<<gAgg, 256, 0, stream>>>(B0, meta_n, csr_n, b2, (char*)partials);
    mean_kernel<<<128, 256, 0, stream>>>(partials, out);
}